// Round 8
// baseline (588.114 us; speedup 1.0000x reference)
//
#include <hip/hip_runtime.h>
#include <math.h>

// Problem constants: B=2, T=2048, D_MODEL=1024, H=16, D=64.
#define TSEQ   2048
#define DMODEL 1024
#define NHEADS 16
#define DHEAD  64
#define BATCH  2

typedef __attribute__((ext_vector_type(8))) short short8;   // 8 bf16 (4 VGPRs)
typedef __attribute__((ext_vector_type(4))) float f32x4;    // MFMA C/D

__device__ __forceinline__ unsigned short f2bf(float x) {
    union { float f; unsigned int u; } c; c.f = x;
    unsigned int r = (c.u + 0x7FFFu + ((c.u >> 16) & 1u)) >> 16;   // RNE
    return (unsigned short)r;
}
__device__ __forceinline__ float bf2f(unsigned short h) {
    union { unsigned int u; float f; } c; c.u = ((unsigned int)h) << 16;
    return c.f;
}
__device__ __forceinline__ void split2(float x, unsigned short& h, unsigned short& l) {
    h = f2bf(x);
    l = f2bf(x - bf2f(h));
}

// ===========================================================================
// NEW PIPELINE (needs 120 MiB ws)
// Prep kernel: (a) split x fp32 -> bf16 hi/lo [m][k];
//              (b) transpose+split W[k][n] fp32 -> Wt[n][k] bf16 hi/lo, 4 mats.
// ===========================================================================
__global__ __launch_bounds__(256) void prep_kernel(
    const float* __restrict__ x,
    const float* __restrict__ Wq, const float* __restrict__ Wk,
    const float* __restrict__ Wv, const float* __restrict__ Wo,
    unsigned short* __restrict__ xhi, unsigned short* __restrict__ xlo,
    unsigned short* __restrict__ wth, unsigned short* __restrict__ wtl)
{
    const int tid = threadIdx.x;
    const int bid = blockIdx.x;
    if (bid < 1024) {
        const size_t base = (size_t)bid * 4096;
        #pragma unroll
        for (int i = 0; i < 4; ++i) {
            const size_t idx = base + (size_t)i * 1024 + tid * 4;
            float4 v = *(const float4*)(x + idx);
            ushort4 h4, l4;
            split2(v.x, h4.x, l4.x); split2(v.y, h4.y, l4.y);
            split2(v.z, h4.z, l4.z); split2(v.w, h4.w, l4.w);
            *(ushort4*)(xhi + idx) = h4;
            *(ushort4*)(xlo + idx) = l4;
        }
    } else {
        __shared__ float tile[64][65];
        const int tv = bid - 1024;
        const int w  = tv >> 8;                 // 0..3 : Wq,Wk,Wv,Wo
        const int kt = (tv & 255) >> 4;
        const int nt = tv & 15;
        const int k0 = kt * 64, n0 = nt * 64;
        const float* __restrict__ W = (w == 0) ? Wq : (w == 1) ? Wk : (w == 2) ? Wv : Wo;
        const int r = tid >> 4;                 // 0..15 (+16i)
        const int c = (tid & 15) * 4;
        #pragma unroll
        for (int i = 0; i < 4; ++i) {
            float4 v = *(const float4*)(W + (size_t)(k0 + r + 16 * i) * DMODEL + n0 + c);
            tile[r + 16 * i][c + 0] = v.x;
            tile[r + 16 * i][c + 1] = v.y;
            tile[r + 16 * i][c + 2] = v.z;
            tile[r + 16 * i][c + 3] = v.w;
        }
        __syncthreads();
        unsigned short* oh = wth + (size_t)w * DMODEL * DMODEL;
        unsigned short* ol = wtl + (size_t)w * DMODEL * DMODEL;
        #pragma unroll
        for (int i = 0; i < 4; ++i) {
            const int a = r + 16 * i;           // n offset within tile
            ushort4 h4, l4;
            split2(tile[c + 0][a], h4.x, l4.x);
            split2(tile[c + 1][a], h4.y, l4.y);
            split2(tile[c + 2][a], h4.z, l4.z);
            split2(tile[c + 3][a], h4.w, l4.w);
            const size_t off = (size_t)(n0 + a) * DMODEL + k0 + c;
            *(ushort4*)(oh + off) = h4;
            *(ushort4*)(ol + off) = l4;
        }
    }
}

// ===========================================================================
// Split-bf16 MFMA GEMM pieces: 128x128 tile, BK=32, 4 waves (2x2).
// LDS rows 64B, XOR chunk swizzle. 3 passes: hh + hl + lh (ll ~2^-18 dropped).
// ===========================================================================
#define LOFF4(r, ch) (((r) << 6) + ((((ch) ^ ((r) & 3))) << 4))

__device__ __forceinline__ short8 frag4(const char* lb, int row, int ch) {
    union { uint4 u; short8 s; } cv;
    cv.u = *(const uint4*)(lb + LOFF4(row, ch));
    return cv.s;
}

#define GEMM_STAGE_DECLS \
    const int sr = tid >> 1;   /* staging row 0..127 */ \
    const int shalf = tid & 1; /* 32B half of 64B row */ \
    uint4 ra[2], rla[2], rb[2], rlb[2];

#define GEMM_LOAD(kk) { \
    const size_t ao = (size_t)arowg * DMODEL + (kk) + shalf * 16; \
    ra[0]  = *(const uint4*)(Ahg + ao);  ra[1]  = *(const uint4*)(Ahg + ao + 8); \
    rla[0] = *(const uint4*)(Alg + ao);  rla[1] = *(const uint4*)(Alg + ao + 8); \
    const size_t bo = (size_t)browg * DMODEL + (kk) + shalf * 16; \
    rb[0]  = *(const uint4*)(Bhg + bo);  rb[1]  = *(const uint4*)(Bhg + bo + 8); \
    rlb[0] = *(const uint4*)(Blg + bo);  rlb[1] = *(const uint4*)(Blg + bo + 8); }

#define GEMM_WRITE_LDS { \
    *(uint4*)(Ah + LOFF4(sr, shalf * 2))     = ra[0]; \
    *(uint4*)(Ah + LOFF4(sr, shalf * 2 + 1)) = ra[1]; \
    *(uint4*)(Al + LOFF4(sr, shalf * 2))     = rla[0]; \
    *(uint4*)(Al + LOFF4(sr, shalf * 2 + 1)) = rla[1]; \
    *(uint4*)(Bh + LOFF4(sr, shalf * 2))     = rb[0]; \
    *(uint4*)(Bh + LOFF4(sr, shalf * 2 + 1)) = rb[1]; \
    *(uint4*)(Bl + LOFF4(sr, shalf * 2))     = rlb[0]; \
    *(uint4*)(Bl + LOFF4(sr, shalf * 2 + 1)) = rlb[1]; }

#define GEMM_COMPUTE { \
    short8 fa[4], fla[4], fb[4], flb[4]; \
    _Pragma("unroll") \
    for (int mi = 0; mi < 4; ++mi) { \
        fa[mi]  = frag4(Ah, wr * 64 + mi * 16 + ln15, g); \
        fla[mi] = frag4(Al, wr * 64 + mi * 16 + ln15, g); \
    } \
    _Pragma("unroll") \
    for (int nj = 0; nj < 4; ++nj) { \
        fb[nj]  = frag4(Bh, wc * 64 + nj * 16 + ln15, g); \
        flb[nj] = frag4(Bl, wc * 64 + nj * 16 + ln15, g); \
    } \
    _Pragma("unroll") \
    for (int mi = 0; mi < 4; ++mi) \
        _Pragma("unroll") \
        for (int nj = 0; nj < 4; ++nj) { \
            acc[mi][nj] = __builtin_amdgcn_mfma_f32_16x16x32_bf16(fa[mi],  fb[nj],  acc[mi][nj], 0, 0, 0); \
            acc[mi][nj] = __builtin_amdgcn_mfma_f32_16x16x32_bf16(fa[mi],  flb[nj], acc[mi][nj], 0, 0, 0); \
            acc[mi][nj] = __builtin_amdgcn_mfma_f32_16x16x32_bf16(fla[mi], fb[nj],  acc[mi][nj], 0, 0, 0); \
        } }

// ===========================================================================
// QKV projection (split-bf16 MFMA) + fused RoPE epilogue.
// ===========================================================================
__global__ __launch_bounds__(256, 2) void qkv_mfma_kernel(
    const unsigned short* __restrict__ xhi, const unsigned short* __restrict__ xlo,
    const unsigned short* __restrict__ wth, const unsigned short* __restrict__ wtl,
    const float* __restrict__ cosb, const float* __restrict__ sinb,
    unsigned short* __restrict__ qhi, unsigned short* __restrict__ qlo,
    unsigned short* __restrict__ khi, unsigned short* __restrict__ klo,
    unsigned short* __restrict__ vto)
{
    __shared__ __align__(16) char smem[32768];
    char* Ah = smem;
    char* Al = smem + 8192;
    char* Bh = smem + 16384;
    char* Bl = smem + 24576;

    const int tid  = threadIdx.x;
    const int lane = tid & 63;
    const int wave = tid >> 6;
    const int ln15 = lane & 15;
    const int g    = lane >> 4;
    const int wr   = wave >> 1;
    const int wc   = wave & 1;

    const int m0    = blockIdx.y * 128;
    const int sec   = blockIdx.x >> 3;            // 0=q,1=k,2=v
    const int nsec0 = (blockIdx.x & 7) * 128;

    const unsigned short* Ahg = xhi;
    const unsigned short* Alg = xlo;
    const unsigned short* Bhg = wth + (size_t)sec * DMODEL * DMODEL;
    const unsigned short* Blg = wtl + (size_t)sec * DMODEL * DMODEL;

    GEMM_STAGE_DECLS
    const int arowg = m0 + sr;
    const int browg = nsec0 + sr;

    f32x4 acc[4][4];
    #pragma unroll
    for (int mi = 0; mi < 4; ++mi)
        #pragma unroll
        for (int nj = 0; nj < 4; ++nj)
            acc[mi][nj] = (f32x4){0.f, 0.f, 0.f, 0.f};

    GEMM_LOAD(0)
    for (int k0 = 0; k0 < DMODEL; k0 += 32) {
        __syncthreads();
        GEMM_WRITE_LDS
        __syncthreads();
        if (k0 + 32 < DMODEL) GEMM_LOAD(k0 + 32)
        GEMM_COMPUTE
    }

    unsigned short* oh = (sec == 0) ? qhi : khi;
    unsigned short* ol = (sec == 0) ? qlo : klo;
    #pragma unroll
    for (int mi = 0; mi < 4; ++mi) {
        #pragma unroll
        for (int nj = 0; nj < 4; ++nj) {
            const int colh = nsec0 + wc * 64 + nj * 16 + ln15;   // 0..1023
            const int h = colh >> 6;
            const int d = colh & 63;
            const int p = d >> 1;
            const float sgn = (d & 1) ? 1.f : -1.f;
            #pragma unroll
            for (int reg = 0; reg < 4; ++reg) {
                const int row = m0 + wr * 64 + mi * 16 + g * 4 + reg;
                const int t = row & (TSEQ - 1);
                const int b = row >> 11;
                float v = acc[mi][nj][reg];
                if (sec < 2) {
                    float pv = __shfl_xor(v, 1);       // partner in RoPE pair
                    float cv = cosb[t * (DHEAD / 2) + p];
                    float sv = sinb[t * (DHEAD / 2) + p];
                    float rv = v * cv + pv * sv * sgn; // even: x1*c-x2*s; odd: x1*s+x2*c
                    unsigned short hh, ll;
                    split2(rv, hh, ll);
                    const size_t off = (((size_t)b * NHEADS + h) * TSEQ + t) * DHEAD + d;
                    oh[off] = hh;
                    ol[off] = ll;
                } else {
                    vto[(((size_t)b * NHEADS + h) * DHEAD + d) * TSEQ + t] = f2bf(v);
                }
            }
        }
    }
}

// ===========================================================================
// Causal flash attention, bf16 MFMA 16x16x32, split-precision QK^T.
// template<SPLITZ>: epilogue writes either fp32 z or bf16 hi/lo z.
// ===========================================================================
#define LDSOFF(r, c) (((r) << 7) + ((((c) ^ ((r) & 7))) << 4))

__device__ __forceinline__ void stage64x64(const unsigned short* __restrict__ gm,
                                           int rs_elems, char* lbase, int tid) {
    const int r = tid >> 3;
    const int c = tid & 7;
    const char* gb = (const char*)gm;
    uint4 v0 = *(const uint4*)(gb + (size_t)r * rs_elems * 2 + (c << 4));
    uint4 v1 = *(const uint4*)(gb + (size_t)(r + 32) * rs_elems * 2 + (c << 4));
    *(uint4*)(lbase + LDSOFF(r, c)) = v0;
    *(uint4*)(lbase + LDSOFF(r + 32, c)) = v1;
}

__device__ __forceinline__ short8 frag(const char* lbase, int row, int chunk) {
    union { uint4 u; short8 s; } cv;
    cv.u = *(const uint4*)(lbase + LDSOFF(row, chunk));
    return cv.s;
}

template<bool SPLITZ>
__global__ __launch_bounds__(256) void attn_mfma_kernel(
    const unsigned short* __restrict__ qhig, const unsigned short* __restrict__ qlog,
    const unsigned short* __restrict__ khig, const unsigned short* __restrict__ klog,
    const unsigned short* __restrict__ vtg,
    float* __restrict__ zf,
    unsigned short* __restrict__ zhi, unsigned short* __restrict__ zlo)
{
    __shared__ __align__(16) char smem[49152];
    char* Qhb = smem;
    char* Qlb = smem + 8192;
    char* Khb = smem + 16384;
    char* Klb = smem + 24576;
    char* Vb  = smem + 32768;
    char* Pb  = smem + 40960;

    const int tid  = threadIdx.x;
    const int lane = tid & 63;
    const int wave = tid >> 6;
    const int ln15 = lane & 15;
    const int g    = lane >> 4;

    const int bh = blockIdx.y;
    const int b  = bh >> 4;
    const int h  = bh & 15;
    const unsigned short* qhh = qhig + (size_t)bh * TSEQ * DHEAD;
    const unsigned short* qlh = qlog + (size_t)bh * TSEQ * DHEAD;
    const unsigned short* khh = khig + (size_t)bh * TSEQ * DHEAD;
    const unsigned short* klh = klog + (size_t)bh * TSEQ * DHEAD;
    const unsigned short* vth = vtg  + (size_t)bh * DHEAD * TSEQ;

    for (int half = 0; half < 2; ++half) {
        const int qt = half ? (31 - (int)blockIdx.x) : (int)blockIdx.x;

        __syncthreads();
        stage64x64(qhh + (size_t)qt * 64 * DHEAD, DHEAD, Qhb, tid);
        stage64x64(qlh + (size_t)qt * 64 * DHEAD, DHEAD, Qlb, tid);
        __syncthreads();

        const int rA = 16 * wave + ln15;
        short8 qh0 = frag(Qhb, rA, g),     qh1 = frag(Qhb, rA, 4 + g);
        short8 ql0 = frag(Qlb, rA, g),     ql1 = frag(Qlb, rA, 4 + g);

        float m_i[4], l_i[4];
        f32x4 oacc[4];
        #pragma unroll
        for (int i2 = 0; i2 < 4; ++i2) {
            m_i[i2] = -INFINITY; l_i[i2] = 0.f;
            oacc[i2][0] = 0.f; oacc[i2][1] = 0.f; oacc[i2][2] = 0.f; oacc[i2][3] = 0.f;
        }

        for (int jt = 0; jt <= qt; ++jt) {
            __syncthreads();
            stage64x64(khh + (size_t)jt * 64 * DHEAD, DHEAD, Khb, tid);
            stage64x64(klh + (size_t)jt * 64 * DHEAD, DHEAD, Klb, tid);
            stage64x64(vth + (size_t)jt * 64, TSEQ, Vb, tid);
            __syncthreads();

            f32x4 sacc[4];
            #pragma unroll
            for (int ct = 0; ct < 4; ++ct) {
                const int rB = ct * 16 + ln15;
                short8 kh0 = frag(Khb, rB, g), kh1 = frag(Khb, rB, 4 + g);
                short8 kl0 = frag(Klb, rB, g), kl1 = frag(Klb, rB, 4 + g);
                f32x4 a2 = {0.f, 0.f, 0.f, 0.f};
                a2 = __builtin_amdgcn_mfma_f32_16x16x32_bf16(qh0, kh0, a2, 0, 0, 0);
                a2 = __builtin_amdgcn_mfma_f32_16x16x32_bf16(qh1, kh1, a2, 0, 0, 0);
                a2 = __builtin_amdgcn_mfma_f32_16x16x32_bf16(qh0, kl0, a2, 0, 0, 0);
                a2 = __builtin_amdgcn_mfma_f32_16x16x32_bf16(qh1, kl1, a2, 0, 0, 0);
                a2 = __builtin_amdgcn_mfma_f32_16x16x32_bf16(ql0, kh0, a2, 0, 0, 0);
                a2 = __builtin_amdgcn_mfma_f32_16x16x32_bf16(ql1, kh1, a2, 0, 0, 0);
                sacc[ct] = a2;
            }

            const bool diag = (jt == qt);
            #pragma unroll
            for (int reg = 0; reg < 4; ++reg) {
                const int rloc = 16 * wave + 4 * g + reg;
                float sv[4];
                #pragma unroll
                for (int ct = 0; ct < 4; ++ct) {
                    float xv = sacc[ct][reg] * 0.125f;
                    if (diag && (ct * 16 + ln15 > rloc)) xv = -INFINITY;
                    sv[ct] = xv;
                }
                float mr = fmaxf(fmaxf(sv[0], sv[1]), fmaxf(sv[2], sv[3]));
                #pragma unroll
                for (int off = 1; off < 16; off <<= 1)
                    mr = fmaxf(mr, __shfl_xor(mr, off));
                float mnew = fmaxf(m_i[reg], mr);
                float al   = __expf(m_i[reg] - mnew);
                float rs = 0.f;
                unsigned short pb[4];
                #pragma unroll
                for (int ct = 0; ct < 4; ++ct) {
                    float pp = __expf(sv[ct] - mnew);
                    pb[ct] = f2bf(pp);
                    rs += bf2f(pb[ct]);
                }
                #pragma unroll
                for (int off = 1; off < 16; off <<= 1)
                    rs += __shfl_xor(rs, off);
                l_i[reg] = l_i[reg] * al + rs;
                m_i[reg] = mnew;
                #pragma unroll
                for (int dt = 0; dt < 4; ++dt)
                    oacc[dt][reg] *= al;
                #pragma unroll
                for (int ct = 0; ct < 4; ++ct) {
                    const int col = ct * 16 + ln15;
                    const int chunk = col >> 3;
                    const int byt = (rloc << 7) + ((chunk ^ (rloc & 7)) << 4) + ((col & 7) << 1);
                    *(unsigned short*)(Pb + byt) = pb[ct];
                }
            }

            short8 pa0 = frag(Pb, rA, g);
            short8 pa1 = frag(Pb, rA, 4 + g);
            #pragma unroll
            for (int dt = 0; dt < 4; ++dt) {
                short8 vb0 = frag(Vb, dt * 16 + ln15, g);
                short8 vb1 = frag(Vb, dt * 16 + ln15, 4 + g);
                oacc[dt] = __builtin_amdgcn_mfma_f32_16x16x32_bf16(pa0, vb0, oacc[dt], 0, 0, 0);
                oacc[dt] = __builtin_amdgcn_mfma_f32_16x16x32_bf16(pa1, vb1, oacc[dt], 0, 0, 0);
            }
        }

        #pragma unroll
        for (int reg = 0; reg < 4; ++reg) {
            const float inv = 1.0f / l_i[reg];
            const int t = qt * 64 + 16 * wave + 4 * g + reg;
            const size_t idx = ((size_t)(b * TSEQ + t)) * DMODEL + h * DHEAD;
            #pragma unroll
            for (int dt = 0; dt < 4; ++dt) {
                float val = oacc[dt][reg] * inv;
                if (SPLITZ) {
                    unsigned short hh = f2bf(val);
                    zhi[idx + dt * 16 + ln15] = hh;
                    zlo[idx + dt * 16 + ln15] = f2bf(val - bf2f(hh));
                } else {
                    zf[idx + dt * 16 + ln15] = val;
                }
            }
        }
    }
}

// ===========================================================================
// Output projection z @ W_out (split-bf16 MFMA), fp32 out.
// ===========================================================================
__global__ __launch_bounds__(256, 2) void out_proj_mfma_kernel(
    const unsigned short* __restrict__ zhi, const unsigned short* __restrict__ zlo,
    const unsigned short* __restrict__ wth, const unsigned short* __restrict__ wtl,
    float* __restrict__ outp)
{
    __shared__ __align__(16) char smem[32768];
    char* Ah = smem;
    char* Al = smem + 8192;
    char* Bh = smem + 16384;
    char* Bl = smem + 24576;

    const int tid  = threadIdx.x;
    const int lane = tid & 63;
    const int wave = tid >> 6;
    const int ln15 = lane & 15;
    const int g    = lane >> 4;
    const int wr   = wave >> 1;
    const int wc   = wave & 1;

    const int m0 = blockIdx.y * 128;
    const int n0 = blockIdx.x * 128;

    const unsigned short* Ahg = zhi;
    const unsigned short* Alg = zlo;
    const unsigned short* Bhg = wth + (size_t)3 * DMODEL * DMODEL;   // Wo
    const unsigned short* Blg = wtl + (size_t)3 * DMODEL * DMODEL;

    GEMM_STAGE_DECLS
    const int arowg = m0 + sr;
    const int browg = n0 + sr;

    f32x4 acc[4][4];
    #pragma unroll
    for (int mi = 0; mi < 4; ++mi)
        #pragma unroll
        for (int nj = 0; nj < 4; ++nj)
            acc[mi][nj] = (f32x4){0.f, 0.f, 0.f, 0.f};

    GEMM_LOAD(0)
    for (int k0 = 0; k0 < DMODEL; k0 += 32) {
        __syncthreads();
        GEMM_WRITE_LDS
        __syncthreads();
        if (k0 + 32 < DMODEL) GEMM_LOAD(k0 + 32)
        GEMM_COMPUTE
    }

    #pragma unroll
    for (int mi = 0; mi < 4; ++mi)
        #pragma unroll
        for (int nj = 0; nj < 4; ++nj) {
            const int col = n0 + wc * 64 + nj * 16 + ln15;
            #pragma unroll
            for (int reg = 0; reg < 4; ++reg) {
                const int row = m0 + wr * 64 + mi * 16 + g * 4 + reg;
                outp[(size_t)row * DMODEL + col] = acc[mi][nj][reg];
            }
        }
}

// ===========================================================================
// FALLBACK PIPELINE (validated round-3; 56 MiB ws): fp32 VALU projections.
// ===========================================================================
__global__ __launch_bounds__(256) void qkv_rope_f32_kernel(
    const float* __restrict__ x,
    const float* __restrict__ Wq, const float* __restrict__ Wk,
    const float* __restrict__ Wv,
    const float* __restrict__ cosb, const float* __restrict__ sinb,
    unsigned short* __restrict__ qhi, unsigned short* __restrict__ qlo,
    unsigned short* __restrict__ khi, unsigned short* __restrict__ klo,
    unsigned short* __restrict__ vto)
{
    __shared__ float As[16][132];
    __shared__ float Bs[16][132];

    const int tid = threadIdx.x;
    const int m0  = blockIdx.y * 128;
    const int n0g = blockIdx.x * 128;
    const int section = n0g >> 10;
    const int n0 = n0g & 1023;
    const float* __restrict__ W = (section == 0) ? Wq : (section == 1) ? Wk : Wv;

    const int arow = tid >> 2;
    const int ak   = (tid & 3) << 2;
    const int brow = tid >> 5;
    const int bn   = (tid & 31) << 2;
    const int rr = (tid & 15) << 2;
    const int cc = (tid >> 4) << 2;

    float acc[2][2][4][4] = {};

    const float* Aptr0 = x + (size_t)(m0 + arow) * DMODEL + ak;
    const float* Aptr1 = Aptr0 + (size_t)64 * DMODEL;
    const float* Bptr0 = W + (size_t)brow * DMODEL + n0 + bn;
    const float* Bptr1 = Bptr0 + (size_t)8 * DMODEL;

    float4 av0 = *(const float4*)(Aptr0);
    float4 av1 = *(const float4*)(Aptr1);
    float4 bv0 = *(const float4*)(Bptr0);
    float4 bv1 = *(const float4*)(Bptr1);

    for (int k0 = 0; k0 < DMODEL; k0 += 16) {
        __syncthreads();
        As[ak + 0][arow] = av0.x;  As[ak + 1][arow] = av0.y;
        As[ak + 2][arow] = av0.z;  As[ak + 3][arow] = av0.w;
        As[ak + 0][arow + 64] = av1.x;  As[ak + 1][arow + 64] = av1.y;
        As[ak + 2][arow + 64] = av1.z;  As[ak + 3][arow + 64] = av1.w;
        *(float4*)&Bs[brow][bn]     = bv0;
        *(float4*)&Bs[brow + 8][bn] = bv1;
        __syncthreads();
        if (k0 + 16 < DMODEL) {
            av0 = *(const float4*)(Aptr0 + k0 + 16);
            av1 = *(const float4*)(Aptr1 + k0 + 16);
            bv0 = *(const float4*)(Bptr0 + (size_t)(k0 + 16) * DMODEL);
            bv1 = *(const float4*)(Bptr1 + (size_t)(k0 + 16) * DMODEL);
        }
        #pragma unroll
        for (int kk = 0; kk < 16; ++kk) {
            float4 a0 = *(const float4*)&As[kk][rr];
            float4 a1 = *(const float4*)&As[kk][rr + 64];
            float4 b0 = *(const float4*)&Bs[kk][cc];
            float4 b1 = *(const float4*)&Bs[kk][cc + 64];
            float ar[2][4] = {{a0.x, a0.y, a0.z, a0.w}, {a1.x, a1.y, a1.z, a1.w}};
            float br[2][4] = {{b0.x, b0.y, b0.z, b0.w}, {b1.x, b1.y, b1.z, b1.w}};
            #pragma unroll
            for (int bi = 0; bi < 2; ++bi)
                #pragma unroll
                for (int i = 0; i < 4; ++i)
                    #pragma unroll
                    for (int bj = 0; bj < 2; ++bj)
                        #pragma unroll
                        for (int jj = 0; jj < 4; ++jj)
                            acc[bi][bj][i][jj] += ar[bi][i] * br[bj][jj];
        }
    }

    const int b = m0 >> 11;
    #pragma unroll
    for (int bi = 0; bi < 2; ++bi) {
        #pragma unroll
        for (int i = 0; i < 4; ++i) {
            const int t = (m0 + bi * 64 + rr + i) & (TSEQ - 1);
            #pragma unroll
            for (int bj = 0; bj < 2; ++bj) {
                const int n  = n0 + bj * 64 + cc;
                const int h  = n >> 6;
                const int d0 = n & 63;
                float a0 = acc[bi][bj][i][0], a1 = acc[bi][bj][i][1];
                float a2 = acc[bi][bj][i][2], a3 = acc[bi][bj][i][3];
                if (section < 2) {
                    const int p0 = d0 >> 1;
                    float c0v = cosb[t * (DHEAD / 2) + p0];
                    float s0v = sinb[t * (DHEAD / 2) + p0];
                    float c1v = cosb[t * (DHEAD / 2) + p0 + 1];
                    float s1v = sinb[t * (DHEAD / 2) + p0 + 1];
                    float r[4];
                    r[0] = a0 * c0v - a1 * s0v;
                    r[1] = a0 * s0v + a1 * c0v;
                    r[2] = a2 * c1v - a3 * s1v;
                    r[3] = a2 * s1v + a3 * c1v;
                    ushort4 uh, ul;
                    split2(r[0], uh.x, ul.x);
                    split2(r[1], uh.y, ul.y);
                    split2(r[2], uh.z, ul.z);
                    split2(r[3], uh.w, ul.w);
                    unsigned short* ph = (section == 0) ? qhi : khi;
                    unsigned short* pl = (section == 0) ? qlo : klo;
                    const size_t off = (((size_t)b * NHEADS + h) * TSEQ + t) * DHEAD + d0;
                    *(ushort4*)&ph[off] = uh;
                    *(ushort4*)&pl[off] = ul;
                } else {
                    const size_t base = ((size_t)b * NHEADS + h) * DHEAD;
                    vto[(base + d0 + 0) * TSEQ + t] = f2bf(a0);
                    vto[(base + d0 + 1) * TSEQ + t] = f2bf(a1);
                    vto[(base + d0 + 2) * TSEQ + t] = f2bf(a2);
                    vto[(base + d0 + 3) * TSEQ + t] = f2bf(a3);
                }
            }
        }
    }
}

__global__ __launch_bounds__(256) void out_proj_f32_kernel(
    const float* __restrict__ A, const float* __restrict__ B,
    float* __restrict__ C)
{
    __shared__ float As[16][132];
    __shared__ float Bs[16][132];

    const int tid = threadIdx.x;
    const int m0 = blockIdx.y * 128;
    const int n0 = blockIdx.x * 128;

    const int arow = tid >> 2;
    const int ak   = (tid & 3) << 2;
    const int brow = tid >> 5;
    const int bn   = (tid & 31) << 2;
    const int rr   = (tid & 15) << 2;
    const int cc   = (tid >> 4) << 2;

    float acc[2][2][4][4] = {};

    const float* Aptr0 = A + (size_t)(m0 + arow) * DMODEL + ak;
    const float* Aptr1 = Aptr0 + (size_t)64 * DMODEL;
    const float* Bptr0 = B + (size_t)brow * DMODEL + n0 + bn;
    const float* Bptr1 = Bptr0 + (size_t)8 * DMODEL;

    float4 av0 = *(const float4*)(Aptr0);
    float4 av1 = *(const float4*)(Aptr1);
    float4 bv0 = *(const float4*)(Bptr0);
    float4 bv1 = *(const float4*)(Bptr1);

    for (int k0 = 0; k0 < DMODEL; k0 += 16) {
        __syncthreads();
        As[ak + 0][arow] = av0.x;  As[ak + 1][arow] = av0.y;
        As[ak + 2][arow] = av0.z;  As[ak + 3][arow] = av0.w;
        As[ak + 0][arow + 64] = av1.x;  As[ak + 1][arow + 64] = av1.y;
        As[ak + 2][arow + 64] = av1.z;  As[ak + 3][arow + 64] = av1.w;
        *(float4*)&Bs[brow][bn]     = bv0;
        *(float4*)&Bs[brow + 8][bn] = bv1;
        __syncthreads();
        if (k0 + 16 < DMODEL) {
            av0 = *(const float4*)(Aptr0 + k0 + 16);
            av1 = *(const float4*)(Aptr1 + k0 + 16);
            bv0 = *(const float4*)(Bptr0 + (size_t)(k0 + 16) * DMODEL);
            bv1 = *(const float4*)(Bptr1 + (size_t)(k0 + 16) * DMODEL);
        }
        #pragma unroll
        for (int kk = 0; kk < 16; ++kk) {
            float4 a0 = *(const float4*)&As[kk][rr];
            float4 a1 = *(const float4*)&As[kk][rr + 64];
            float4 b0 = *(const float4*)&Bs[kk][cc];
            float4 b1 = *(const float4*)&Bs[kk][cc + 64];
            float ar[2][4] = {{a0.x, a0.y, a0.z, a0.w}, {a1.x, a1.y, a1.z, a1.w}};
            float br[2][4] = {{b0.x, b0.y, b0.z, b0.w}, {b1.x, b1.y, b1.z, b1.w}};
            #pragma unroll
            for (int bi = 0; bi < 2; ++bi)
                #pragma unroll
                for (int i = 0; i < 4; ++i)
                    #pragma unroll
                    for (int bj = 0; bj < 2; ++bj)
                        #pragma unroll
                        for (int jj = 0; jj < 4; ++jj)
                            acc[bi][bj][i][jj] += ar[bi][i] * br[bj][jj];
        }
    }

    #pragma unroll
    for (int bi = 0; bi < 2; ++bi)
        #pragma unroll
        for (int i = 0; i < 4; ++i) {
            const size_t row = m0 + bi * 64 + rr + i;
            #pragma unroll
            for (int bj = 0; bj < 2; ++bj) {
                const int col = n0 + bj * 64 + cc;
                *(float4*)&C[row * DMODEL + col] =
                    make_float4(acc[bi][bj][i][0], acc[bi][bj][i][1],
                                acc[bi][bj][i][2], acc[bi][bj][i][3]);
            }
        }
}

// ===========================================================================
// Launcher. New pipeline ws (ushort units of `per`): xhi|xlo|wth(4)|wtl(4)|
// qhi|qlo|khi|klo|vt = 15*per*2 = 120 MiB. Fallback: 5*per*2 + 16 MiB = 56 MiB.
// Branch on ws_size is constant across calls (graph-capture safe).
// ===========================================================================
extern "C" void kernel_launch(void* const* d_in, const int* in_sizes, int n_in,
                              void* d_out, int out_size, void* d_ws, size_t ws_size,
                              hipStream_t stream)
{
    const float* x    = (const float*)d_in[0];
    const float* cosb = (const float*)d_in[1];
    const float* sinb = (const float*)d_in[2];
    const float* Wq   = (const float*)d_in[3];
    const float* Wk   = (const float*)d_in[4];
    const float* Wv   = (const float*)d_in[5];
    const float* Wo   = (const float*)d_in[6];
    float* outp = (float*)d_out;

    const size_t per = (size_t)BATCH * NHEADS * TSEQ * DHEAD;  // 4,194,304
    const size_t need_new = 15 * per * sizeof(unsigned short); // 120 MiB

    if (ws_size >= need_new) {
        unsigned short* xhi = (unsigned short*)d_ws;           // also zhi after attn
        unsigned short* xlo = xhi + per;                       // also zlo
        unsigned short* wth = xlo + per;                       // 4 matrices
        unsigned short* wtl = wth + 4 * per;
        unsigned short* qhi = wtl + 4 * per;
        unsigned short* qlo = qhi + per;
        unsigned short* khi = qlo + per;
        unsigned short* klo = khi + per;
        unsigned short* vt  = klo + per;

        prep_kernel<<<2048, 256, 0, stream>>>(x, Wq, Wk, Wv, Wo, xhi, xlo, wth, wtl);
        qkv_mfma_kernel<<<dim3(24, 32), 256, 0, stream>>>(xhi, xlo, wth, wtl,
                                                          cosb, sinb,
                                                          qhi, qlo, khi, klo, vt);
        attn_mfma_kernel<true><<<dim3(16, 32), 256, 0, stream>>>(
            qhi, qlo, khi, klo, vt, nullptr, xhi, xlo);        // z -> x buffers
        out_proj_mfma_kernel<<<dim3(8, 32), 256, 0, stream>>>(xhi, xlo, wth, wtl, outp);
    } else {
        unsigned short* qhi = (unsigned short*)d_ws;
        unsigned short* qlo = qhi + per;
        unsigned short* khi = qlo + per;
        unsigned short* klo = khi + per;
        unsigned short* vt  = klo + per;
        float* z = (float*)(vt + per);

        qkv_rope_f32_kernel<<<dim3(24, 32), 256, 0, stream>>>(
            x, Wq, Wk, Wv, cosb, sinb, qhi, qlo, khi, klo, vt);
        attn_mfma_kernel<false><<<dim3(16, 32), 256, 0, stream>>>(
            qhi, qlo, khi, klo, vt, z, nullptr, nullptr);
        out_proj_f32_kernel<<<dim3(8, 32), 256, 0, stream>>>(z, Wo, outp);
    }
}